// Round 7
// baseline (47.031 us; speedup 1.0000x reference)
//
#include <hip/hip_runtime.h>
#include <math.h>

// Directional Chamfer: sum_m min_n ||t_m - s_n||^2.
// q = 2 t.s - |s|^2 (maximize), d2 = |t|^2 - qmax.
// Main kernel is LDS-free: scan pairs are wave-uniform -> compiler issues
// s_load_dwordx8; SGPR pairs feed v_pk_fma_f32 directly ("s" operand).
// Pack kernel pre-shuffles scan into SoA-pair layout:
//   pair p -> {2x0,2x1,2y0,2y1} , {2z0,2z1,-n0,-n1}.

typedef float v2 __attribute__((ext_vector_type(2)));

#define TPT 8
#define BLK 256
#define MPB (TPT * BLK)   // 2048 templates per block
#define PPC 40            // scan PAIRS per chunk (80 points; 250*80 = 20000)
#define RED1 25           // chunks folded per reduce1 group

// d = a*b + c per 32-bit half; b comes from an SGPR pair (1 scalar read).
__device__ __forceinline__ v2 pk_fma_vsv(v2 a, v2 b_s, v2 c) {
    v2 d;
    asm("v_pk_fma_f32 %0, %1, %2, %3" : "=v"(d) : "v"(a), "s"(b_s), "v"(c));
    return d;
}
__device__ __forceinline__ float max3(float a, float b, float c) {
    float d;
    asm("v_max3_f32 %0, %1, %2, %3" : "=v"(d) : "v"(a), "v"(b), "v"(c));
    return d;
}

__global__ void __launch_bounds__(256) pack_pairs(
    const float* __restrict__ scan, float4* __restrict__ pk,
    unsigned* __restrict__ counter, int N) {
    if (blockIdx.x == 0 && threadIdx.x == 0) *counter = 0u;
    int p = blockIdx.x * 256 + threadIdx.x;
    int npair = (N + 1) >> 1;
    if (p >= npair) return;
    int i0 = 2 * p, i1 = 2 * p + 1;
    float x0 = scan[3 * i0 + 0], y0 = scan[3 * i0 + 1], z0 = scan[3 * i0 + 2];
    float n0 = x0 * x0 + y0 * y0 + z0 * z0;
    float x1 = 0.f, y1 = 0.f, z1 = 0.f, w1 = -INFINITY;  // inert hi half
    if (i1 < N) {
        x1 = scan[3 * i1 + 0];
        y1 = scan[3 * i1 + 1];
        z1 = scan[3 * i1 + 2];
        w1 = -(x1 * x1 + y1 * y1 + z1 * z1);
    }
    pk[2 * p + 0] = make_float4(2.f * x0, 2.f * x1, 2.f * y0, 2.f * y1);
    pk[2 * p + 1] = make_float4(2.f * z0, 2.f * z1, -n0, w1);
}

__global__ void __launch_bounds__(BLK) chamfer_main(
    const float4* __restrict__ pk, const float* __restrict__ tmpl,
    float* __restrict__ part, int M, int npair) {
    int c = blockIdx.y;
    int p0 = c * PPC;
    int pcnt = npair - p0;
    if (pcnt > PPC) pcnt = PPC;
    if (pcnt < 0) pcnt = 0;

    int base = blockIdx.x * MPB + threadIdx.x;
    v2 txx[TPT], tyy[TPT], tzz[TPT];
    float q[TPT];
#pragma unroll
    for (int k = 0; k < TPT; ++k) {
        int m = base + k * BLK;
        float x = 0.f, y = 0.f, z = 0.f;
        if (m < M) {
            x = tmpl[3 * m + 0];
            y = tmpl[3 * m + 1];
            z = tmpl[3 * m + 2];
        }
        txx[k] = (v2){x, x};
        tyy[k] = (v2){y, y};
        tzz[k] = (v2){z, z};
        q[k] = -INFINITY;
    }

    const float4* bp = pk + (size_t)p0 * 2;
#pragma unroll 2
    for (int p = 0; p < pcnt; ++p) {
        float4 A = bp[2 * p + 0];  // {2x0,2x1,2y0,2y1} — wave-uniform (SMEM)
        float4 B = bp[2 * p + 1];  // {2z0,2z1,-n0,-n1}
        v2 xx = (v2){A.x, A.y};
        v2 yy = (v2){A.z, A.w};
        v2 zz = (v2){B.x, B.y};
        v2 ww = (v2){B.z, B.w};   // "v" use -> 2 v_movs, amortized over TPT
#pragma unroll
        for (int k = 0; k < TPT; ++k) {
            v2 r = pk_fma_vsv(tzz[k], zz, ww);
            r = pk_fma_vsv(tyy[k], yy, r);
            r = pk_fma_vsv(txx[k], xx, r);
            q[k] = max3(q[k], r.x, r.y);
        }
    }

#pragma unroll
    for (int k = 0; k < TPT; ++k) {
        int m = base + k * BLK;
        if (m < M) part[(size_t)c * M + m] = q[k];
    }
}

// Level-1 chunk-max: grid (ceil(M/256), G), depth RED1, unrolled.
__global__ void __launch_bounds__(256) chamfer_reduce1(
    const float* __restrict__ part, float* __restrict__ qpart, int M, int NC) {
    int m = blockIdx.x * 256 + threadIdx.x;
    int g = blockIdx.y;
    if (m >= M) return;
    float qmax = -INFINITY;
#pragma unroll
    for (int c = 0; c < RED1; ++c) {
        int cc = g * RED1 + c;
        if (cc < NC) qmax = fmaxf(qmax, part[(size_t)cc * M + m]);
    }
    qpart[(size_t)g * M + m] = qmax;
}

// Level-2 max + d2 + fixed-order block sums + ticketed last-block final sum.
__global__ void __launch_bounds__(256) chamfer_reduce2(
    const float* __restrict__ tmpl, const float* __restrict__ qpart,
    float* __restrict__ blockSums, unsigned* __restrict__ counter,
    float* __restrict__ out, int M, int G, int nb) {
    int bx = blockIdx.x;
    int m = bx * 256 + threadIdx.x;
    float d2 = 0.f;
    if (m < M) {
        float qmax = -INFINITY;
        for (int g = 0; g < G; ++g)
            qmax = fmaxf(qmax, qpart[(size_t)g * M + m]);
        float x = tmpl[3 * m + 0];
        float y = tmpl[3 * m + 1];
        float z = tmpl[3 * m + 2];
        d2 = fmaf(x, x, fmaf(y, y, z * z)) - qmax;
        if (d2 < 0.f) d2 = 0.f;
    }
    for (int off = 32; off >= 1; off >>= 1) d2 += __shfl_down(d2, off, 64);
    __shared__ float wsum[4];
    __shared__ int islast;
    int lane = threadIdx.x & 63;
    int wid = threadIdx.x >> 6;
    if (lane == 0) wsum[wid] = d2;
    __syncthreads();
    if (threadIdx.x == 0) {
        float bs = wsum[0] + wsum[1] + wsum[2] + wsum[3];
        __hip_atomic_store(&blockSums[bx], bs, __ATOMIC_RELEASE,
                           __HIP_MEMORY_SCOPE_AGENT);
        unsigned t = __hip_atomic_fetch_add(counter, 1u, __ATOMIC_ACQ_REL,
                                            __HIP_MEMORY_SCOPE_AGENT);
        islast = (t == (unsigned)(nb - 1));
    }
    __syncthreads();
    if (islast) {
        float s = 0.f;
        for (int i = threadIdx.x; i < nb; i += 64)
            s += __hip_atomic_load(&blockSums[i], __ATOMIC_RELAXED,
                                   __HIP_MEMORY_SCOPE_AGENT);
        if (threadIdx.x < 64) {
            for (int off = 32; off >= 1; off >>= 1)
                s += __shfl_down(s, off, 64);
            if (threadIdx.x == 0) out[0] = s;
        }
    }
}

extern "C" void kernel_launch(void* const* d_in, const int* in_sizes, int n_in,
                              void* d_out, int out_size, void* d_ws,
                              size_t ws_size, hipStream_t stream) {
    const float* scan = (const float*)d_in[0];   // [N,3]
    const float* tmpl = (const float*)d_in[1];   // [M,3]
    int N = in_sizes[0] / 3;
    int M = in_sizes[1] / 3;
    float* out = (float*)d_out;

    int npair = (N + 1) >> 1;                 // 10000
    int GX = (M + MPB - 1) / MPB;             // 5
    int NC = (npair + PPC - 1) / PPC;         // 250
    int G = (NC + RED1 - 1) / RED1;           // 10
    int MB = (M + 255) / 256;                 // 40

    char* ws = (char*)d_ws;
    unsigned* counter = (unsigned*)ws;                      // @0
    float* blockSums = (float*)(ws + 256);                  // MB floats
    float* qpart = (float*)(ws + 4096);                     // G*M floats
    size_t off = 4096 + ((size_t)G * M * 4 + 255) / 256 * 256;
    float* part = (float*)(ws + off);                       // NC*M floats
    off += ((size_t)NC * M * 4 + 255) / 256 * 256;
    float4* packed = (float4*)(ws + off);                   // 2*npair float4

    pack_pairs<<<(npair + 255) / 256, 256, 0, stream>>>(scan, packed, counter,
                                                        N);
    dim3 grid(GX, NC);
    chamfer_main<<<grid, BLK, 0, stream>>>(packed, tmpl, part, M, npair);
    dim3 rgrid(MB, G);
    chamfer_reduce1<<<rgrid, 256, 0, stream>>>(part, qpart, M, NC);
    chamfer_reduce2<<<MB, 256, 0, stream>>>(tmpl, qpart, blockSums, counter,
                                            out, M, G, MB);
}

// Round 8
// 43.270 us; speedup vs baseline: 1.0869x; 1.0869x over previous
//
#include <hip/hip_runtime.h>
#include <math.h>

// Directional Chamfer: sum_m min_n ||t_m - s_n||^2.
// q = 2 t.s - |s|^2 (maximize), d2 = |t|^2 - qmax.
// 2 dispatches:
//   1) chamfer_main: LDS pair-packed broadcast + v_pk_fma_f32/v_max3_f32,
//      TPT=8 templates/thread. Also zeroes the ticket counters (so replays
//      and the 0xAA ws poison can't corrupt the ticket protocol).
//   2) chamfer_reduce_fused: grid (40,10) dataflow-ticket reduction —
//      20-chunk max -> qpart; last g-block per bx: 10-way max + d2 +
//      fixed-order block sum; last block overall: fixed-order final sum.

typedef float v2 __attribute__((ext_vector_type(2)));

#define TPT 8
#define BLK 256
#define MPB (TPT * BLK)   // 2048 templates per block
#define CHUNK 100         // scan points per chunk (200*100 = 20000 exactly)
#define RED1 20           // chunks folded per reduce group
#define NCTR 64           // counters: [0..39] per-stripe, [40] global

__device__ __forceinline__ v2 pk_fma(v2 a, v2 b, v2 c) {
    v2 d;
    asm("v_pk_fma_f32 %0, %1, %2, %3" : "=v"(d) : "v"(a), "v"(b), "v"(c));
    return d;
}
__device__ __forceinline__ float max3(float a, float b, float c) {
    float d;
    asm("v_max3_f32 %0, %1, %2, %3" : "=v"(d) : "v"(a), "v"(b), "v"(c));
    return d;
}

__global__ void __launch_bounds__(BLK) chamfer_main(
    const float* __restrict__ scan, const float* __restrict__ tmpl,
    float* __restrict__ part, unsigned* __restrict__ counters, int M, int N) {
    __shared__ float4 lds4[(CHUNK + 1) / 2 * 2];
    float* ldsf = (float*)lds4;

    // Zero all tickets (reduce kernel runs strictly after us on the stream).
    if (blockIdx.x == 0 && blockIdx.y == 0 && threadIdx.x < NCTR)
        __hip_atomic_store(&counters[threadIdx.x], 0u, __ATOMIC_RELAXED,
                           __HIP_MEMORY_SCOPE_AGENT);

    int c = blockIdx.y;
    int j0 = c * CHUNK;
    int cnt = N - j0;
    if (cnt > CHUNK) cnt = CHUNK;

    for (int i = threadIdx.x; i < cnt; i += BLK) {
        float x = scan[3 * (j0 + i) + 0];
        float y = scan[3 * (j0 + i) + 1];
        float z = scan[3 * (j0 + i) + 2];
        float* bp = &ldsf[(i >> 1) * 8];
        int h = i & 1;
        bp[0 + h] = 2.f * x;
        bp[2 + h] = 2.f * y;
        bp[4 + h] = 2.f * z;
        bp[6 + h] = -(x * x + y * y + z * z);
    }
    if ((cnt & 1) && threadIdx.x == 0) {  // pad odd tail so hi half is inert
        float* bp = &ldsf[(cnt >> 1) * 8];
        bp[1] = 0.f; bp[3] = 0.f; bp[5] = 0.f; bp[7] = -INFINITY;
    }
    __syncthreads();

    int base = blockIdx.x * MPB + threadIdx.x;
    v2 txx[TPT], tyy[TPT], tzz[TPT];
    float q[TPT];
#pragma unroll
    for (int k = 0; k < TPT; ++k) {
        int m = base + k * BLK;
        float x = 0.f, y = 0.f, z = 0.f;
        if (m < M) {
            x = tmpl[3 * m + 0];
            y = tmpl[3 * m + 1];
            z = tmpl[3 * m + 2];
        }
        txx[k] = (v2){x, x};
        tyy[k] = (v2){y, y};
        tzz[k] = (v2){z, z};
        q[k] = -INFINITY;
    }

    int npair = (cnt + 1) >> 1;
#pragma unroll 2
    for (int p = 0; p < npair; ++p) {
        float4 a = lds4[2 * p + 0];  // broadcast read: {2x0,2x1,2y0,2y1}
        float4 b = lds4[2 * p + 1];  // {2z0,2z1,-n0,-n1}
        v2 xx = (v2){a.x, a.y};
        v2 yy = (v2){a.z, a.w};
        v2 zz = (v2){b.x, b.y};
        v2 ww = (v2){b.z, b.w};
#pragma unroll
        for (int k = 0; k < TPT; ++k) {
            v2 r = pk_fma(tzz[k], zz, ww);
            r = pk_fma(tyy[k], yy, r);
            r = pk_fma(txx[k], xx, r);
            q[k] = max3(q[k], r.x, r.y);
        }
    }

#pragma unroll
    for (int k = 0; k < TPT; ++k) {
        int m = base + k * BLK;
        if (m < M) part[(size_t)c * M + m] = q[k];
    }
}

// Fused reduce with dataflow tickets. Grid (MB=40, G=10), 256 threads.
__global__ void __launch_bounds__(256) chamfer_reduce_fused(
    const float* __restrict__ tmpl, const float* __restrict__ part,
    float* __restrict__ qpart, float* __restrict__ blockSums,
    unsigned* __restrict__ counters, float* __restrict__ out,
    int M, int NC, int G, int nbx) {
    int bx = blockIdx.x;
    int g = blockIdx.y;
    int m = bx * 256 + threadIdx.x;

    // Stage 1: 20-chunk max for this (stripe, group).
    if (m < M) {
        float qmax = -INFINITY;
#pragma unroll
        for (int c = 0; c < RED1; ++c) {
            int cc = g * RED1 + c;
            if (cc < NC) qmax = fmaxf(qmax, part[(size_t)cc * M + m]);
        }
        __hip_atomic_store(&qpart[(size_t)g * M + m], qmax, __ATOMIC_RELAXED,
                           __HIP_MEMORY_SCOPE_AGENT);
    }
    __syncthreads();  // drains vmcnt: stores complete before ticket

    __shared__ int slast;
    if (threadIdx.x == 0) {
        unsigned t = __hip_atomic_fetch_add(&counters[bx], 1u,
                                            __ATOMIC_ACQ_REL,
                                            __HIP_MEMORY_SCOPE_AGENT);
        slast = (t == (unsigned)(G - 1));
    }
    __syncthreads();
    if (!slast) return;

    // Stage 2 (last g-block for bx): 10-way max + d2 + block sum.
    float d2 = 0.f;
    if (m < M) {
        float qmax = -INFINITY;
        for (int g2 = 0; g2 < G; ++g2)
            qmax = fmaxf(qmax, __hip_atomic_load(&qpart[(size_t)g2 * M + m],
                                                 __ATOMIC_RELAXED,
                                                 __HIP_MEMORY_SCOPE_AGENT));
        float x = tmpl[3 * m + 0];
        float y = tmpl[3 * m + 1];
        float z = tmpl[3 * m + 2];
        d2 = fmaf(x, x, fmaf(y, y, z * z)) - qmax;
        if (d2 < 0.f) d2 = 0.f;
    }
    for (int off = 32; off >= 1; off >>= 1) d2 += __shfl_down(d2, off, 64);
    __shared__ float wsum[4];
    __shared__ int slast2;
    int lane = threadIdx.x & 63;
    int wid = threadIdx.x >> 6;
    if (lane == 0) wsum[wid] = d2;
    __syncthreads();
    if (threadIdx.x == 0) {
        float bs = wsum[0] + wsum[1] + wsum[2] + wsum[3];
        __hip_atomic_store(&blockSums[bx], bs, __ATOMIC_RELEASE,
                           __HIP_MEMORY_SCOPE_AGENT);
        unsigned t = __hip_atomic_fetch_add(&counters[nbx], 1u,
                                            __ATOMIC_ACQ_REL,
                                            __HIP_MEMORY_SCOPE_AGENT);
        slast2 = (t == (unsigned)(nbx - 1));
    }
    __syncthreads();
    if (slast2 && threadIdx.x < 64) {
        // Stage 3 (last block overall): fixed-order final sum.
        float s = 0.f;
        for (int i = threadIdx.x; i < nbx; i += 64)
            s += __hip_atomic_load(&blockSums[i], __ATOMIC_RELAXED,
                                   __HIP_MEMORY_SCOPE_AGENT);
        for (int off = 32; off >= 1; off >>= 1) s += __shfl_down(s, off, 64);
        if (threadIdx.x == 0) out[0] = s;
    }
}

extern "C" void kernel_launch(void* const* d_in, const int* in_sizes, int n_in,
                              void* d_out, int out_size, void* d_ws,
                              size_t ws_size, hipStream_t stream) {
    const float* scan = (const float*)d_in[0];   // [N,3]
    const float* tmpl = (const float*)d_in[1];   // [M,3]
    int N = in_sizes[0] / 3;
    int M = in_sizes[1] / 3;
    float* out = (float*)d_out;

    int GX = (M + MPB - 1) / MPB;        // 5
    int NC = (N + CHUNK - 1) / CHUNK;    // 200
    int G = (NC + RED1 - 1) / RED1;      // 10
    int MB = (M + 255) / 256;            // 40

    char* ws = (char*)d_ws;
    unsigned* counters = (unsigned*)ws;                     // NCTR u32 @0
    float* blockSums = (float*)(ws + 1024);                 // MB floats
    float* qpart = (float*)(ws + 4096);                     // G*M floats
    size_t off = 4096 + ((size_t)G * M * 4 + 255) / 256 * 256;
    float* part = (float*)(ws + off);                       // NC*M floats

    dim3 grid(GX, NC);
    chamfer_main<<<grid, BLK, 0, stream>>>(scan, tmpl, part, counters, M, N);
    dim3 rgrid(MB, G);
    chamfer_reduce_fused<<<rgrid, 256, 0, stream>>>(tmpl, part, qpart,
                                                    blockSums, counters, out,
                                                    M, NC, G, MB);
}